// Round 16
// baseline (62.091 us; speedup 1.0000x reference)
//
#include <hip/hip_runtime.h>
#include <hip/hip_bf16.h>

typedef __bf16 bf16;
typedef __bf16 bf16x4 __attribute__((ext_vector_type(4)));
typedef __bf16 bf16x8 __attribute__((ext_vector_type(8)));
typedef float f32x4 __attribute__((ext_vector_type(4)));

#define NB 8
#define NT 2048
#define NC 1024
#define NH 64

// 0.125 * log2(e): folds the attention scale AND the exp->exp2 conversion into Wq
#define QSCALE 0.18033688011112042f
// fixed softmax shift (log2 units): logits have std~1.4, max~8 -> 16 is safe
// (f32 overflow only if a logit exceeded 143; relative precision is scale-invariant)
#define FIXM 16.0f

__device__ inline f32x4 zero4() {
    f32x4 z; z[0] = 0.f; z[1] = 0.f; z[2] = 0.f; z[3] = 0.f; return z;
}

// raw v_exp_f32 (2^x): avoids llvm.exp2's denormal-safe multi-op expansion.
__device__ inline float fast_exp2(float x) {
    float r;
    asm volatile("v_exp_f32 %0, %1" : "=v"(r) : "v"(x));
    return r;
}

// ---------------- pack W into MFMA-fragment order ----------------
// Wt2[(((nf*16+kt)*2+kc)*64+l)*8+e] = W^T[n = nf*16+(l&15)][k = kt*64+kc*32+(l>>4)*8+e]
// Wq rows (n<64) pre-scaled by QSCALE so QK^T logits arrive in log2 units.
__global__ __launch_bounds__(256) void pack_w(const float* __restrict__ Wq,
                                              const float* __restrict__ Wk,
                                              const float* __restrict__ Wv,
                                              bf16* __restrict__ Wt2) {
    const int g = blockIdx.x * 256 + threadIdx.x;   // 0..24575
    const int l = g & 63;
    const int kc = (g >> 6) & 1;
    const int kt = (g >> 7) & 15;
    const int nf = g >> 11;                          // 0..11
    const int n = nf * 16 + (l & 15);
    const int k0 = kt * 64 + kc * 32 + (l >> 4) * 8;
    const float* W = (n < 64) ? Wq : (n < 128) ? Wk : Wv;
    const float sc = (n < 64) ? QSCALE : 1.0f;
    const int h = n & 63;
    bf16x8 o;
#pragma unroll
    for (int e = 0; e < 8; ++e) o[e] = (bf16)(W[(k0 + e) * NH + h] * sc);
    *reinterpret_cast<bf16x8*>(Wt2 + (size_t)g * 8) = o;
}

// ---------------- QKV projection (R14 exact — best known) ----------------
// 256 blocks x 512 threads = 64 rows x 192 cols, 8 waves = qh(2, 32-row) x ch(4, 48-col).
__global__ __launch_bounds__(512, 2) void qkv_gemm(const float* __restrict__ x,
                                                   const bf16* __restrict__ Wt2,
                                                   bf16* __restrict__ qp,
                                                   bf16* __restrict__ kp2,
                                                   bf16* __restrict__ vt2) {
    __shared__ bf16 xs[2][64][72];   // double-buffered, +8 pad (18432 B)
    const int tid = threadIdx.x;
    const int wave = tid >> 6, lane = tid & 63;
    const int l16 = lane & 15, lhi = lane >> 4;
    const int qh = wave & 1;      // 32-row half
    const int ch = wave >> 1;     // 48-col quarter (3 nf frags)
    const int row0 = blockIdx.x * 64;
    const bf16* wb = Wt2 + (size_t)(ch * 3) * 16384 + lane * 8;   // + nf*16384 + kt*1024 + kc*512

    f32x4 acc[2][3];   // [mr][nf]
#pragma unroll
    for (int mr = 0; mr < 2; ++mr)
#pragma unroll
        for (int nf = 0; nf < 3; ++nf) acc[mr][nf] = zero4();

    const int sr = tid >> 4;           // 0..31 (rows sr, sr+32)
    const int sc = (tid & 15) * 4;     // f32 col

    float4 xv[3][2];     // 3-deep x pipeline, 2 rows/thread
    bf16x8 bfr[2][6];    // B-fragment double buffer

#define LOAD_X(SLOT, KT)  do { \
    xv[SLOT][0] = *reinterpret_cast<const float4*>(&x[(size_t)(row0 + sr) * NC + (KT) * 64 + sc]); \
    xv[SLOT][1] = *reinterpret_cast<const float4*>(&x[(size_t)(row0 + sr + 32) * NC + (KT) * 64 + sc]); \
} while (0)

#define LOAD_B(SLOT, KT)  do { \
    _Pragma("unroll") for (int _nf = 0; _nf < 3; ++_nf) \
        _Pragma("unroll") for (int _kc = 0; _kc < 2; ++_kc) \
            bfr[SLOT][_nf * 2 + _kc] = *reinterpret_cast<const bf16x8*>( \
                wb + _nf * 16384 + (KT) * 1024 + _kc * 512); \
} while (0)

#define WRITE_XS(BUF, SLOT)  do { \
    bf16x4 _w0, _w1; \
    _w0[0] = (bf16)xv[SLOT][0].x; _w0[1] = (bf16)xv[SLOT][0].y; \
    _w0[2] = (bf16)xv[SLOT][0].z; _w0[3] = (bf16)xv[SLOT][0].w; \
    _w1[0] = (bf16)xv[SLOT][1].x; _w1[1] = (bf16)xv[SLOT][1].y; \
    _w1[2] = (bf16)xv[SLOT][1].z; _w1[3] = (bf16)xv[SLOT][1].w; \
    *reinterpret_cast<bf16x4*>(&xs[BUF][sr][sc]) = _w0; \
    *reinterpret_cast<bf16x4*>(&xs[BUF][sr + 32][sc]) = _w1; \
} while (0)

    LOAD_X(0, 0);
    LOAD_X(1, 1);
    LOAD_X(2, 2);
    LOAD_B(0, 0);
    WRITE_XS(0, 0);
    __syncthreads();

#pragma unroll
    for (int kt = 0; kt < 16; ++kt) {
        const int cur = kt & 1, nxt = cur ^ 1;
        if (kt < 13) LOAD_X(kt % 3, kt + 3);
        bf16x8 a[2][2];   // [mr][kc]
#pragma unroll
        for (int mr = 0; mr < 2; ++mr)
#pragma unroll
            for (int kc = 0; kc < 2; ++kc)
                a[mr][kc] = *reinterpret_cast<const bf16x8*>(
                    &xs[cur][qh * 32 + mr * 16 + l16][kc * 32 + lhi * 8]);
        if (kt < 15) WRITE_XS(nxt, (kt + 1) % 3);
        if (kt < 15) LOAD_B(nxt, kt + 1);
        __syncthreads();
        __builtin_amdgcn_s_setprio(1);
#pragma unroll
        for (int nf = 0; nf < 3; ++nf)
#pragma unroll
            for (int kc = 0; kc < 2; ++kc)
#pragma unroll
                for (int mr = 0; mr < 2; ++mr)
                    acc[mr][nf] = __builtin_amdgcn_mfma_f32_16x16x32_bf16(
                        a[mr][kc], bfr[cur][nf * 2 + kc], acc[mr][nf], 0, 0, 0);
        __builtin_amdgcn_s_setprio(0);
    }
#undef LOAD_X
#undef LOAD_B
#undef WRITE_XS

    // epilogue: q row-major; k,v scattered into fragment-order kp2/vt2
    // (direct 2-B scatters: each block's k/v region is one contiguous 8 KB ->
    //  L2 write-combining absorbs it; R15's LDS-staged variant was slower)
#pragma unroll
    for (int mr = 0; mr < 2; ++mr)
#pragma unroll
    for (int nf = 0; nf < 3; ++nf) {
        const int col = ch * 48 + nf * 16 + l16;
#pragma unroll
        for (int r = 0; r < 4; ++r) {
            const int row = row0 + qh * 32 + mr * 16 + lhi * 4 + r;
            const bf16 val = (bf16)acc[mr][nf][r];
            const int bb = row >> 11, kv = row & (NT - 1);
            const int t = kv >> 6;
            if (col < 64) {
                qp[(size_t)row * NH + col] = val;
            } else if (col < 128) {
                const int h = col - 64;
                const int kvb = (kv >> 4) & 3;
                const int lK = ((h & 31) >> 3) * 16 + (kv & 15);
                kp2[((((size_t)(bb * 32 + t) * 4 + kvb) * 2 + (h >> 5)) * 64 + lK) * 8 + (h & 7)] = val;
            } else {
                const int h = col - 128;
                const int kcV = (kv >> 5) & 1;
                const int lV = ((kv & 31) >> 3) * 16 + (h & 15);
                vt2[((((size_t)(bb * 32 + t) * 2 + kcV) * 4 + (h >> 4)) * 64 + lV) * 8 + (kv & 7)] = val;
            }
        }
    }
}

// ---------------- fused flash attention ----------------
// R14 geometry: grid (32, 8), 512 threads = 8 waves = kvsplit(4) x qpair(2).
// FIXED-M softmax: P = exp2(s - 16). No max tracking, no rescale, no per-iter
// cross-lane reduce (row-sum deferred to one shfl pair after the loop).
// Critical path per iter: QK-MFMA -> exp -> pack -> PV.
__global__ __launch_bounds__(512, 2) void attn(const bf16* __restrict__ qp,
                                               const bf16* __restrict__ kp2,
                                               const bf16* __restrict__ vt2,
                                               const int* __restrict__ mask,
                                               float* __restrict__ out) {
    __shared__ __align__(16) char smem[4 * 64 * 68 * 4];   // 69632 B (union)
    bf16 (*p_lds)[64][20] = reinterpret_cast<bf16 (*)[64][20]>(smem);   // [8][64][20] = 20480 B
    float (*sm_o)[64][68] = reinterpret_cast<float (*)[64][68]>(smem);  // [4][64][68]
    __shared__ float sm_l[4][64];

    const int tid = threadIdx.x;
    const int wave = tid >> 6, lane = tid & 63;
    const int l16 = lane & 15, lhi = lane >> 4;
    const int sp = wave & 3;                    // KV split
    const int qg = wave >> 2;                   // q pair half
    const int b = blockIdx.y;
    const int q_blk = blockIdx.x * 64;
    const int q_base = q_blk + qg * 32;         // this wave's 32 q-rows
    const int tb = sp * 8;                      // first 64-row KV tile of this split
    bf16* const pw = &p_lds[wave][0][0];

    // Q fragments for both q-tiles (q pre-scaled by 0.125*log2e at pack time)
    bf16x8 aq[2][2];
#pragma unroll
    for (int t = 0; t < 2; ++t)
#pragma unroll
        for (int hc = 0; hc < 2; ++hc)
            aq[t][hc] = *reinterpret_cast<const bf16x8*>(
                &qp[((size_t)b * NT + q_base + t * 16 + l16) * NH + hc * 32 + lhi * 8]);

    const bf16* kw = kp2 + (size_t)b * 131072 + (size_t)tb * 4096 + lane * 8;
    const bf16* vw = vt2 + (size_t)b * 131072 + (size_t)tb * 4096 + lane * 8;
    const int*  mw = mask + b * NT + tb * 64 + lhi * 4;

    float lac[2] = {0.f, 0.f};   // lane-local partial row sums (reduced after loop)
    f32x4 o[2][4];
#pragma unroll
    for (int t = 0; t < 2; ++t)
#pragma unroll
        for (int hb = 0; hb < 4; ++hb) o[t][hb] = zero4();

#pragma unroll
    for (int it = 0; it < 8; ++it) {
        const int fo = it * 4096;   // one 64-row KV tile
        // ---- K + mask loads (one-clause frags) ----
        bf16x8 kf[8];   // [kvb][hc]
#pragma unroll
        for (int i = 0; i < 8; ++i)
            kf[i] = *reinterpret_cast<const bf16x8*>(kw + fo + i * 512);
        int4 mv[4];
#pragma unroll
        for (int kvb = 0; kvb < 4; ++kvb)
            mv[kvb] = *reinterpret_cast<const int4*>(mw + it * 64 + kvb * 16);
        // ---- QK^T for both q-tiles (swapped: A=K, B=Q); logits in log2 units ----
        f32x4 s[2][4];
        __builtin_amdgcn_s_setprio(1);
#pragma unroll
        for (int t = 0; t < 2; ++t)
#pragma unroll
            for (int kvb = 0; kvb < 4; ++kvb) {
                s[t][kvb] = zero4();
                s[t][kvb] = __builtin_amdgcn_mfma_f32_16x16x32_bf16(kf[kvb * 2], aq[t][0], s[t][kvb], 0, 0, 0);
                s[t][kvb] = __builtin_amdgcn_mfma_f32_16x16x32_bf16(kf[kvb * 2 + 1], aq[t][1], s[t][kvb], 0, 0, 0);
            }
        __builtin_amdgcn_s_setprio(0);
        // ---- V loads (latency hides under softmax) ----
        bf16x8 vf[8];   // [kc][hb]
#pragma unroll
        for (int i = 0; i < 8; ++i)
            vf[i] = *reinterpret_cast<const bf16x8*>(vw + fo + i * 512);
        // ---- mask: wave-uniform all-ones fast path ----
        const int okm = (mv[0].x != 0) & (mv[0].y != 0) & (mv[0].z != 0) & (mv[0].w != 0) &
                        (mv[1].x != 0) & (mv[1].y != 0) & (mv[1].z != 0) & (mv[1].w != 0) &
                        (mv[2].x != 0) & (mv[2].y != 0) & (mv[2].z != 0) & (mv[2].w != 0) &
                        (mv[3].x != 0) & (mv[3].y != 0) & (mv[3].z != 0) & (mv[3].w != 0);
        const bool allone = __all(okm);
        f32x4 biasv[4];
        if (!allone) {
#pragma unroll
            for (int kvb = 0; kvb < 4; ++kvb) {
                biasv[kvb][0] = mv[kvb].x ? 0.f : -1e30f;
                biasv[kvb][1] = mv[kvb].y ? 0.f : -1e30f;
                biasv[kvb][2] = mv[kvb].z ? 0.f : -1e30f;
                biasv[kvb][3] = mv[kvb].w ? 0.f : -1e30f;
            }
        }
        // ---- per q-tile: P = exp2(s - FIXM), pack, PV ----
#pragma unroll
        for (int t = 0; t < 2; ++t) {
            if (!allone) {
#pragma unroll
                for (int kvb = 0; kvb < 4; ++kvb) s[t][kvb] += biasv[kvb];
            }
            float ps = 0.f;
#pragma unroll
            for (int kvb = 0; kvb < 4; ++kvb)
#pragma unroll
                for (int r = 0; r < 4; ++r) {
                    const float p = fast_exp2(s[t][kvb][r] - FIXM);
                    s[t][kvb][r] = p;
                    ps += p;
                }
            lac[t] += ps;
            // pack P -> wave-private LDS (A-frag order); in-wave DS order is safe
#pragma unroll
            for (int kvb = 0; kvb < 4; ++kvb) {
                bf16x4 w;
                w[0] = (bf16)s[t][kvb][0]; w[1] = (bf16)s[t][kvb][1];
                w[2] = (bf16)s[t][kvb][2]; w[3] = (bf16)s[t][kvb][3];
                const int row = l16 + 16 * ((kvb * 2 + (lhi >> 1)) & 3);
                *reinterpret_cast<bf16x4*>(pw + row * 20 + (kvb >> 1) * 8 + (lhi & 1) * 4) = w;
            }
            // O += P V
            __builtin_amdgcn_s_setprio(1);
#pragma unroll
            for (int kc = 0; kc < 2; ++kc) {
                const bf16* pr = pw + lane * 20 + kc * 8;
                const bf16x4 lo = *reinterpret_cast<const bf16x4*>(pr);
                const bf16x4 hi = *reinterpret_cast<const bf16x4*>(pr + 4);
                const bf16x8 pa = __builtin_shufflevector(lo, hi, 0, 1, 2, 3, 4, 5, 6, 7);
#pragma unroll
                for (int hb = 0; hb < 4; ++hb)
                    o[t][hb] = __builtin_amdgcn_mfma_f32_16x16x32_bf16(pa, vf[kc * 4 + hb], o[t][hb], 0, 0, 0);
            }
            __builtin_amdgcn_s_setprio(0);
        }
    }

    // ---- one deferred row-sum reduce per q-tile ----
#pragma unroll
    for (int t = 0; t < 2; ++t) {
        lac[t] += __shfl_xor(lac[t], 16);
        lac[t] += __shfl_xor(lac[t], 32);
    }

    // ---- combine the 4 KV splits through LDS (no max: common fixed M) ----
    __syncthreads();   // all waves done with p_lds (aliased by sm_o)
#pragma unroll
    for (int t = 0; t < 2; ++t) {
        const int rbase = qg * 32 + t * 16;
#pragma unroll
        for (int hb = 0; hb < 4; ++hb)
#pragma unroll
            for (int r = 0; r < 4; ++r)
                sm_o[sp][rbase + lhi * 4 + r][hb * 16 + l16] = o[t][hb][r];
        if (lhi == 0)
            sm_l[sp][rbase + l16] = lac[t];
    }
    __syncthreads();

#pragma unroll
    for (int e = 0; e < 8; ++e) {
        const int idx = e * 512 + tid;      // 0..4095
        const int row = idx >> 6;           // 0..63
        const int col = idx & 63;
        float L = 0.f, accv = 0.f;
#pragma unroll
        for (int s2 = 0; s2 < 4; ++s2) {
            L += sm_l[s2][row];
            accv += sm_o[s2][row][col];
        }
        out[((size_t)b * NT + q_blk + row) * NH + col] = accv / L;
    }
}

extern "C" void kernel_launch(void* const* d_in, const int* in_sizes, int n_in,
                              void* d_out, int out_size, void* d_ws, size_t ws_size,
                              hipStream_t stream) {
    const float* x    = (const float*)d_in[0];
    const int*   mask = (const int*)d_in[1];
    const float* Wk   = (const float*)d_in[2];
    const float* Wq   = (const float*)d_in[3];
    const float* Wv   = (const float*)d_in[4];
    float* out = (float*)d_out;

    char* ws = (char*)d_ws;
    bf16* Wt2 = (bf16*)(ws);                                  // 384 KiB
    bf16* qp  = (bf16*)(ws + (512 << 10));                    // 2 MiB
    bf16* kp2 = (bf16*)(ws + (512 << 10) + (2 << 20));        // 2 MiB
    bf16* vt2 = (bf16*)(ws + (512 << 10) + (4 << 20));        // 2 MiB

    pack_w<<<dim3(96), dim3(256), 0, stream>>>(Wq, Wk, Wv, Wt2);
    qkv_gemm<<<dim3(256), dim3(512), 0, stream>>>(x, Wt2, qp, kp2, vt2);
    attn<<<dim3(32, 8), dim3(512), 0, stream>>>(qp, kp2, vt2, mask, out);
}

// Round 17
// 44.880 us; speedup vs baseline: 1.3835x; 1.3835x over previous
//
#include <hip/hip_runtime.h>
#include <hip/hip_bf16.h>

typedef __bf16 bf16;
typedef __bf16 bf16x4 __attribute__((ext_vector_type(4)));
typedef __bf16 bf16x8 __attribute__((ext_vector_type(8)));
typedef float f32x4 __attribute__((ext_vector_type(4)));

#define NB 8
#define NT 2048
#define NC 1024
#define NH 64

// 0.125 * log2(e): folds the attention scale AND the exp->exp2 conversion into Wq
#define QSCALE 0.18033688011112042f

__device__ inline f32x4 zero4() {
    f32x4 z; z[0] = 0.f; z[1] = 0.f; z[2] = 0.f; z[3] = 0.f; return z;
}

// raw v_exp_f32 (2^x): avoids llvm.exp2's denormal-safe multi-op expansion.
__device__ inline float fast_exp2(float x) {
    float r;
    asm volatile("v_exp_f32 %0, %1" : "=v"(r) : "v"(x));
    return r;
}

// ---------------- pack W into MFMA-fragment order ----------------
// Wt2[(((nf*16+kt)*2+kc)*64+l)*8+e] = W^T[n = nf*16+(l&15)][k = kt*64+kc*32+(l>>4)*8+e]
// Wq rows (n<64) pre-scaled by QSCALE so QK^T logits arrive in log2 units.
__global__ __launch_bounds__(256) void pack_w(const float* __restrict__ Wq,
                                              const float* __restrict__ Wk,
                                              const float* __restrict__ Wv,
                                              bf16* __restrict__ Wt2) {
    const int g = blockIdx.x * 256 + threadIdx.x;   // 0..24575
    const int l = g & 63;
    const int kc = (g >> 6) & 1;
    const int kt = (g >> 7) & 15;
    const int nf = g >> 11;                          // 0..11
    const int n = nf * 16 + (l & 15);
    const int k0 = kt * 64 + kc * 32 + (l >> 4) * 8;
    const float* W = (n < 64) ? Wq : (n < 128) ? Wk : Wv;
    const float sc = (n < 64) ? QSCALE : 1.0f;
    const int h = n & 63;
    bf16x8 o;
#pragma unroll
    for (int e = 0; e < 8; ++e) o[e] = (bf16)(W[(k0 + e) * NH + h] * sc);
    *reinterpret_cast<bf16x8*>(Wt2 + (size_t)g * 8) = o;
}

// ---------------- QKV projection (R14 exact — best known) ----------------
// 256 blocks x 512 threads = 64 rows x 192 cols, 8 waves = qh(2, 32-row) x ch(4, 48-col).
__global__ __launch_bounds__(512, 2) void qkv_gemm(const float* __restrict__ x,
                                                   const bf16* __restrict__ Wt2,
                                                   bf16* __restrict__ qp,
                                                   bf16* __restrict__ kp2,
                                                   bf16* __restrict__ vt2) {
    __shared__ bf16 xs[2][64][72];   // double-buffered, +8 pad (18432 B)
    const int tid = threadIdx.x;
    const int wave = tid >> 6, lane = tid & 63;
    const int l16 = lane & 15, lhi = lane >> 4;
    const int qh = wave & 1;      // 32-row half
    const int ch = wave >> 1;     // 48-col quarter (3 nf frags)
    const int row0 = blockIdx.x * 64;
    const bf16* wb = Wt2 + (size_t)(ch * 3) * 16384 + lane * 8;   // + nf*16384 + kt*1024 + kc*512

    f32x4 acc[2][3];   // [mr][nf]
#pragma unroll
    for (int mr = 0; mr < 2; ++mr)
#pragma unroll
        for (int nf = 0; nf < 3; ++nf) acc[mr][nf] = zero4();

    const int sr = tid >> 4;           // 0..31 (rows sr, sr+32)
    const int sc = (tid & 15) * 4;     // f32 col

    float4 xv[3][2];     // 3-deep x pipeline, 2 rows/thread
    bf16x8 bfr[2][6];    // B-fragment double buffer

#define LOAD_X(SLOT, KT)  do { \
    xv[SLOT][0] = *reinterpret_cast<const float4*>(&x[(size_t)(row0 + sr) * NC + (KT) * 64 + sc]); \
    xv[SLOT][1] = *reinterpret_cast<const float4*>(&x[(size_t)(row0 + sr + 32) * NC + (KT) * 64 + sc]); \
} while (0)

#define LOAD_B(SLOT, KT)  do { \
    _Pragma("unroll") for (int _nf = 0; _nf < 3; ++_nf) \
        _Pragma("unroll") for (int _kc = 0; _kc < 2; ++_kc) \
            bfr[SLOT][_nf * 2 + _kc] = *reinterpret_cast<const bf16x8*>( \
                wb + _nf * 16384 + (KT) * 1024 + _kc * 512); \
} while (0)

#define WRITE_XS(BUF, SLOT)  do { \
    bf16x4 _w0, _w1; \
    _w0[0] = (bf16)xv[SLOT][0].x; _w0[1] = (bf16)xv[SLOT][0].y; \
    _w0[2] = (bf16)xv[SLOT][0].z; _w0[3] = (bf16)xv[SLOT][0].w; \
    _w1[0] = (bf16)xv[SLOT][1].x; _w1[1] = (bf16)xv[SLOT][1].y; \
    _w1[2] = (bf16)xv[SLOT][1].z; _w1[3] = (bf16)xv[SLOT][1].w; \
    *reinterpret_cast<bf16x4*>(&xs[BUF][sr][sc]) = _w0; \
    *reinterpret_cast<bf16x4*>(&xs[BUF][sr + 32][sc]) = _w1; \
} while (0)

    LOAD_X(0, 0);
    LOAD_X(1, 1);
    LOAD_X(2, 2);
    LOAD_B(0, 0);
    WRITE_XS(0, 0);
    __syncthreads();

#pragma unroll
    for (int kt = 0; kt < 16; ++kt) {
        const int cur = kt & 1, nxt = cur ^ 1;
        if (kt < 13) LOAD_X(kt % 3, kt + 3);
        bf16x8 a[2][2];   // [mr][kc]
#pragma unroll
        for (int mr = 0; mr < 2; ++mr)
#pragma unroll
            for (int kc = 0; kc < 2; ++kc)
                a[mr][kc] = *reinterpret_cast<const bf16x8*>(
                    &xs[cur][qh * 32 + mr * 16 + l16][kc * 32 + lhi * 8]);
        if (kt < 15) WRITE_XS(nxt, (kt + 1) % 3);
        if (kt < 15) LOAD_B(nxt, kt + 1);
        __syncthreads();
        __builtin_amdgcn_s_setprio(1);
#pragma unroll
        for (int nf = 0; nf < 3; ++nf)
#pragma unroll
            for (int kc = 0; kc < 2; ++kc)
#pragma unroll
                for (int mr = 0; mr < 2; ++mr)
                    acc[mr][nf] = __builtin_amdgcn_mfma_f32_16x16x32_bf16(
                        a[mr][kc], bfr[cur][nf * 2 + kc], acc[mr][nf], 0, 0, 0);
        __builtin_amdgcn_s_setprio(0);
    }
#undef LOAD_X
#undef LOAD_B
#undef WRITE_XS

    // epilogue: q row-major; k,v scattered into fragment-order kp2/vt2
    // (direct 2-B scatters: each block's k/v region is one contiguous 8 KB ->
    //  L2 write-combining absorbs it; R15's LDS-staged variant was slower)
#pragma unroll
    for (int mr = 0; mr < 2; ++mr)
#pragma unroll
    for (int nf = 0; nf < 3; ++nf) {
        const int col = ch * 48 + nf * 16 + l16;
#pragma unroll
        for (int r = 0; r < 4; ++r) {
            const int row = row0 + qh * 32 + mr * 16 + lhi * 4 + r;
            const bf16 val = (bf16)acc[mr][nf][r];
            const int bb = row >> 11, kv = row & (NT - 1);
            const int t = kv >> 6;
            if (col < 64) {
                qp[(size_t)row * NH + col] = val;
            } else if (col < 128) {
                const int h = col - 64;
                const int kvb = (kv >> 4) & 3;
                const int lK = ((h & 31) >> 3) * 16 + (kv & 15);
                kp2[((((size_t)(bb * 32 + t) * 4 + kvb) * 2 + (h >> 5)) * 64 + lK) * 8 + (h & 7)] = val;
            } else {
                const int h = col - 128;
                const int kcV = (kv >> 5) & 1;
                const int lV = ((kv & 31) >> 3) * 16 + (h & 15);
                vt2[((((size_t)(bb * 32 + t) * 2 + kcV) * 4 + (h >> 4)) * 64 + lV) * 8 + (kv & 7)] = val;
            }
        }
    }
}

// ---------------- fused flash attention (R14 exact — best known) ----------------
// grid (32, 8): 64 q-rows/block. 512 threads = 8 waves = kvsplit(4) x qpair(2).
// Online softmax with defer-max: the max-tree + shfls between V-load and PV-use
// also separate register lifetimes — removing them (R16) caused VGPR spills.
__global__ __launch_bounds__(512, 2) void attn(const bf16* __restrict__ qp,
                                               const bf16* __restrict__ kp2,
                                               const bf16* __restrict__ vt2,
                                               const int* __restrict__ mask,
                                               float* __restrict__ out) {
    __shared__ __align__(16) char smem[4 * 64 * 68 * 4];   // 69632 B (union)
    bf16 (*p_lds)[64][20] = reinterpret_cast<bf16 (*)[64][20]>(smem);   // [8][64][20] = 20480 B
    float (*sm_o)[64][68] = reinterpret_cast<float (*)[64][68]>(smem);  // [4][64][68]
    __shared__ float sm_m[4][64], sm_l[4][64];

    const int tid = threadIdx.x;
    const int wave = tid >> 6, lane = tid & 63;
    const int l16 = lane & 15, lhi = lane >> 4;
    const int sp = wave & 3;                    // KV split
    const int qg = wave >> 2;                   // q pair half
    const int b = blockIdx.y;
    const int q_blk = blockIdx.x * 64;
    const int q_base = q_blk + qg * 32;         // this wave's 32 q-rows
    const int tb = sp * 8;                      // first 64-row KV tile of this split
    bf16* const pw = &p_lds[wave][0][0];

    // Q fragments for both q-tiles (q pre-scaled by 0.125*log2e at pack time)
    bf16x8 aq[2][2];
#pragma unroll
    for (int t = 0; t < 2; ++t)
#pragma unroll
        for (int hc = 0; hc < 2; ++hc)
            aq[t][hc] = *reinterpret_cast<const bf16x8*>(
                &qp[((size_t)b * NT + q_base + t * 16 + l16) * NH + hc * 32 + lhi * 8]);

    const bf16* kw = kp2 + (size_t)b * 131072 + (size_t)tb * 4096 + lane * 8;
    const bf16* vw = vt2 + (size_t)b * 131072 + (size_t)tb * 4096 + lane * 8;
    const int*  mw = mask + b * NT + tb * 64 + lhi * 4;

    float m[2] = {-1e30f, -1e30f}, l[2] = {0.f, 0.f};
    f32x4 o[2][4];
#pragma unroll
    for (int t = 0; t < 2; ++t)
#pragma unroll
        for (int hb = 0; hb < 4; ++hb) o[t][hb] = zero4();

#pragma unroll
    for (int it = 0; it < 8; ++it) {
        const int fo = it * 4096;   // one 64-row KV tile
        // ---- K + mask loads (one-clause frags) ----
        bf16x8 kf[8];   // [kvb][hc]
#pragma unroll
        for (int i = 0; i < 8; ++i)
            kf[i] = *reinterpret_cast<const bf16x8*>(kw + fo + i * 512);
        int4 mv[4];
#pragma unroll
        for (int kvb = 0; kvb < 4; ++kvb)
            mv[kvb] = *reinterpret_cast<const int4*>(mw + it * 64 + kvb * 16);
        // ---- QK^T for both q-tiles (swapped: A=K, B=Q); logits in log2 units ----
        f32x4 s[2][4];
        __builtin_amdgcn_s_setprio(1);
#pragma unroll
        for (int t = 0; t < 2; ++t)
#pragma unroll
            for (int kvb = 0; kvb < 4; ++kvb) {
                s[t][kvb] = zero4();
                s[t][kvb] = __builtin_amdgcn_mfma_f32_16x16x32_bf16(kf[kvb * 2], aq[t][0], s[t][kvb], 0, 0, 0);
                s[t][kvb] = __builtin_amdgcn_mfma_f32_16x16x32_bf16(kf[kvb * 2 + 1], aq[t][1], s[t][kvb], 0, 0, 0);
            }
        __builtin_amdgcn_s_setprio(0);
        // ---- V loads (latency hides under softmax) ----
        bf16x8 vf[8];   // [kc][hb]
#pragma unroll
        for (int i = 0; i < 8; ++i)
            vf[i] = *reinterpret_cast<const bf16x8*>(vw + fo + i * 512);
        // ---- mask: wave-uniform all-ones fast path ----
        const int okm = (mv[0].x != 0) & (mv[0].y != 0) & (mv[0].z != 0) & (mv[0].w != 0) &
                        (mv[1].x != 0) & (mv[1].y != 0) & (mv[1].z != 0) & (mv[1].w != 0) &
                        (mv[2].x != 0) & (mv[2].y != 0) & (mv[2].z != 0) & (mv[2].w != 0) &
                        (mv[3].x != 0) & (mv[3].y != 0) & (mv[3].z != 0) & (mv[3].w != 0);
        const bool allone = __all(okm);
        f32x4 biasv[4];
        if (!allone) {
#pragma unroll
            for (int kvb = 0; kvb < 4; ++kvb) {
                biasv[kvb][0] = mv[kvb].x ? 0.f : -1e30f;
                biasv[kvb][1] = mv[kvb].y ? 0.f : -1e30f;
                biasv[kvb][2] = mv[kvb].z ? 0.f : -1e30f;
                biasv[kvb][3] = mv[kvb].w ? 0.f : -1e30f;
            }
        }
        // ---- per q-tile: softmax + P pack + PV ----
#pragma unroll
        for (int t = 0; t < 2; ++t) {
            if (!allone) {
#pragma unroll
                for (int kvb = 0; kvb < 4; ++kvb) s[t][kvb] += biasv[kvb];
            }
            float tm = s[t][0][0];
#pragma unroll
            for (int kvb = 0; kvb < 4; ++kvb)
#pragma unroll
                for (int r = 0; r < 4; ++r) tm = fmaxf(tm, s[t][kvb][r]);
            tm = fmaxf(tm, __shfl_xor(tm, 16));
            tm = fmaxf(tm, __shfl_xor(tm, 32));
            // defer-max: rescale only when max grows by > 8 (log2 units)
            if (!__all(tm <= m[t] + 8.f)) {
                const float mn = fmaxf(m[t], tm);
                const float alpha = fast_exp2(m[t] - mn);
                m[t] = mn;
                l[t] *= alpha;
                float ar[4];
#pragma unroll
                for (int r = 0; r < 4; ++r) ar[r] = __shfl(alpha, lhi * 4 + r);
#pragma unroll
                for (int hb = 0; hb < 4; ++hb)
#pragma unroll
                    for (int r = 0; r < 4; ++r) o[t][hb][r] *= ar[r];
            }
            float ps = 0.f;
#pragma unroll
            for (int kvb = 0; kvb < 4; ++kvb)
#pragma unroll
                for (int r = 0; r < 4; ++r) {
                    const float p = fast_exp2(s[t][kvb][r] - m[t]);
                    s[t][kvb][r] = p;
                    ps += p;
                }
            ps += __shfl_xor(ps, 16);
            ps += __shfl_xor(ps, 32);
            l[t] += ps;
            // pack P -> wave-private LDS (A-frag order); in-wave DS order is safe
#pragma unroll
            for (int kvb = 0; kvb < 4; ++kvb) {
                bf16x4 w;
                w[0] = (bf16)s[t][kvb][0]; w[1] = (bf16)s[t][kvb][1];
                w[2] = (bf16)s[t][kvb][2]; w[3] = (bf16)s[t][kvb][3];
                const int row = l16 + 16 * ((kvb * 2 + (lhi >> 1)) & 3);
                *reinterpret_cast<bf16x4*>(pw + row * 20 + (kvb >> 1) * 8 + (lhi & 1) * 4) = w;
            }
            // O += P V
            __builtin_amdgcn_s_setprio(1);
#pragma unroll
            for (int kc = 0; kc < 2; ++kc) {
                const bf16* pr = pw + lane * 20 + kc * 8;
                const bf16x4 lo = *reinterpret_cast<const bf16x4*>(pr);
                const bf16x4 hi = *reinterpret_cast<const bf16x4*>(pr + 4);
                const bf16x8 pa = __builtin_shufflevector(lo, hi, 0, 1, 2, 3, 4, 5, 6, 7);
#pragma unroll
                for (int hb = 0; hb < 4; ++hb)
                    o[t][hb] = __builtin_amdgcn_mfma_f32_16x16x32_bf16(pa, vf[kc * 4 + hb], o[t][hb], 0, 0, 0);
            }
            __builtin_amdgcn_s_setprio(0);
        }
    }

    // ---- combine the 4 KV splits through LDS ----
    __syncthreads();   // all waves done with p_lds (aliased by sm_o)
#pragma unroll
    for (int t = 0; t < 2; ++t) {
        const int rbase = qg * 32 + t * 16;
#pragma unroll
        for (int hb = 0; hb < 4; ++hb)
#pragma unroll
            for (int r = 0; r < 4; ++r)
                sm_o[sp][rbase + lhi * 4 + r][hb * 16 + l16] = o[t][hb][r];
        if (lhi == 0) {
            sm_m[sp][rbase + l16] = m[t];
            sm_l[sp][rbase + l16] = l[t];
        }
    }
    __syncthreads();

#pragma unroll
    for (int e = 0; e < 8; ++e) {
        const int idx = e * 512 + tid;      // 0..4095
        const int row = idx >> 6;           // 0..63
        const int col = idx & 63;
        float M = sm_m[0][row];
#pragma unroll
        for (int s2 = 1; s2 < 4; ++s2) M = fmaxf(M, sm_m[s2][row]);
        float L = 0.f, accv = 0.f;
#pragma unroll
        for (int s2 = 0; s2 < 4; ++s2) {
            const float w = fast_exp2(sm_m[s2][row] - M);
            L += w * sm_l[s2][row];
            accv += w * sm_o[s2][row][col];
        }
        out[((size_t)b * NT + q_blk + row) * NH + col] = accv / L;
    }
}

extern "C" void kernel_launch(void* const* d_in, const int* in_sizes, int n_in,
                              void* d_out, int out_size, void* d_ws, size_t ws_size,
                              hipStream_t stream) {
    const float* x    = (const float*)d_in[0];
    const int*   mask = (const int*)d_in[1];
    const float* Wk   = (const float*)d_in[2];
    const float* Wq   = (const float*)d_in[3];
    const float* Wv   = (const float*)d_in[4];
    float* out = (float*)d_out;

    char* ws = (char*)d_ws;
    bf16* Wt2 = (bf16*)(ws);                                  // 384 KiB
    bf16* qp  = (bf16*)(ws + (512 << 10));                    // 2 MiB
    bf16* kp2 = (bf16*)(ws + (512 << 10) + (2 << 20));        // 2 MiB
    bf16* vt2 = (bf16*)(ws + (512 << 10) + (4 << 20));        // 2 MiB

    pack_w<<<dim3(96), dim3(256), 0, stream>>>(Wq, Wk, Wv, Wt2);
    qkv_gemm<<<dim3(256), dim3(512), 0, stream>>>(x, Wt2, qp, kp2, vt2);
    attn<<<dim3(32, 8), dim3(512), 0, stream>>>(qp, kp2, vt2, mask, out);
}